// Round 5
// baseline (822.325 us; speedup 1.0000x reference)
//
#include <hip/hip_runtime.h>

#define HID 2048
#define INTER 1408
#define NEXP 14
#define SINTER 2816
#define TTOK 2048
#define BK 32
#define BM 384

#define GLU_SH 132   // 44 n-tiles x 3 m-slices(768 rows) — heavy-first
#define GLU_RT 308   // 22 n-tiles x 14 experts
#define DWN_SH 96    // 16 n-tiles x 6 m-slices(384 rows)
#define DWN_RT 224   // 16 n-tiles x 14 experts

typedef short bf16x8 __attribute__((ext_vector_type(8)));
typedef float f32x4 __attribute__((ext_vector_type(4)));
typedef unsigned short u16x8 __attribute__((ext_vector_type(8)));

__device__ __forceinline__ unsigned short f2bf(float f) {
    __bf16 b = (__bf16)f;
    return __builtin_bit_cast(unsigned short, b);
}
__device__ __forceinline__ float bf2f(unsigned short u) {
    unsigned v = (unsigned)u << 16;
    return __builtin_bit_cast(float, v);
}
// XOR swizzle for 128B-stride rows (epilogue tiles)
__device__ __forceinline__ unsigned swz(unsigned b) { return b ^ (((b >> 7) & 7u) << 4); }

__device__ __forceinline__ void gload16(const void* g, void* l) {
    __builtin_amdgcn_global_load_lds((__attribute__((address_space(1))) void*)g,
                                     (__attribute__((address_space(3))) void*)l, 16, 0, 0);
}
// raw barrier: no vmcnt drain (keeps prefetch in flight); sched fences stop compiler motion
__device__ __forceinline__ void bsync() {
    __builtin_amdgcn_sched_barrier(0);
    __builtin_amdgcn_s_barrier();
    __builtin_amdgcn_sched_barrier(0);
}
#define WAIT_VM3 asm volatile("s_waitcnt vmcnt(3)" ::: "memory")
#define WAIT_VM1 asm volatile("s_waitcnt vmcnt(1)" ::: "memory")
#define WAIT_VM0 asm volatile("s_waitcnt vmcnt(0)" ::: "memory")
#define WAIT_LGKM0 asm volatile("s_waitcnt lgkmcnt(0)" ::: "memory")

__global__ void k_zero(int* cnt) {
    if ((int)threadIdx.x < NEXP) cnt[threadIdx.x] = 0;
}

__global__ __launch_bounds__(256) void k_xcvt(const float* __restrict__ x,
                                              unsigned short* __restrict__ xb) {
    size_t i = ((size_t)blockIdx.x * 256 + threadIdx.x) * 8;
    float4 a = *(const float4*)(x + i);
    float4 b = *(const float4*)(x + i + 4);
    u16x8 v;
    v[0] = f2bf(a.x); v[1] = f2bf(a.y); v[2] = f2bf(a.z); v[3] = f2bf(a.w);
    v[4] = f2bf(b.x); v[5] = f2bf(b.y); v[6] = f2bf(b.z); v[7] = f2bf(b.w);
    *(u16x8*)(xb + i) = v;
}

__global__ __launch_bounds__(256) void k_router(
    const float* __restrict__ x,
    const float* __restrict__ gate_w, const float* __restrict__ cls_w,
    const float* __restrict__ escale, const float* __restrict__ ebias,
    int* __restrict__ cnt, int* __restrict__ etok, float* __restrict__ ew) {
    const int lane = threadIdx.x & 63;
    const int tok = blockIdx.x * 4 + (threadIdx.x >> 6);
    const float* xr = x + (size_t)tok * HID;
    float xv[32];
#pragma unroll
    for (int i = 0; i < 32; i++) xv[i] = xr[lane + 64 * i];

    float sc[NEXP];
    float mx = 0.f;
#pragma unroll
    for (int e = 0; e < NEXP; e++) {
        const float* cw = cls_w + (size_t)e * HID;
        const float* gw = gate_w + (size_t)e * HID;
        float pc = 0.f, pg = 0.f;
#pragma unroll
        for (int i = 0; i < 32; i++) {
            float v = xv[i];
            pc = fmaf(v, cw[lane + 64 * i], pc);
            pg = fmaf(v, gw[lane + 64 * i], pg);
        }
#pragma unroll
        for (int o = 32; o >= 1; o >>= 1) {
            pc += __shfl_xor(pc, o);
            pg += __shfl_xor(pg, o);
        }
        float lg = pc * (pg / (1.f + __expf(-pg)));
        sc[e] = fabsf(lg);
        mx = fmaxf(mx, sc[e]);
    }
    float s = 0.f;
#pragma unroll
    for (int e = 0; e < NEXP; e++) { sc[e] = __expf(sc[e] - mx); s += sc[e]; }
    float inv = 1.f / s;
    int i1 = -1, i2 = -1;
    float b1 = -1e30f, b2 = -1e30f, v1 = 0.f, v2 = 0.f;
#pragma unroll
    for (int e = 0; e < NEXP; e++) {
        float sv = sc[e] * inv;
        float b = sv + ebias[e];
        if (b > b1) { b2 = b1; i2 = i1; v2 = v1; b1 = b; i1 = e; v1 = sv; }
        else if (b > b2) { b2 = b; i2 = e; v2 = sv; }
    }
    if (lane == 0) {
        float w1 = 1.f + v1 * escale[i1];
        float w2 = 1.f + v2 * escale[i2];
        int p1 = atomicAdd(&cnt[i1], 1);
        etok[i1 * TTOK + p1] = tok * 2;     ew[i1 * TTOK + p1] = w1;
        int p2 = atomicAdd(&cnt[i2], 1);
        etok[i2 * TTOK + p2] = tok * 2 + 1; ew[i2 * TTOK + p2] = w2;
    }
}

__global__ void k_offsets(const int* __restrict__ cnt, int* __restrict__ offs) {
    if (threadIdx.x == 0) {
        int a = 0;
        for (int e = 0; e < NEXP; e++) { offs[e] = a; a += cnt[e]; }
    }
}

// Fused gate+up GEMM. BM=384, 64 G + 64 U cols, BK=32, 1024 thr / 16 waves.
// A dbuf via global_load_lds; B fp32->bf16 reg-carry; counted-vmcnt pipeline.
__global__ __launch_bounds__(1024) void k_glu5(
    const unsigned short* __restrict__ xb,
    const float* __restrict__ wg, const float* __restrict__ wu,
    const float* __restrict__ sg, const float* __restrict__ su,
    unsigned short* __restrict__ abuf, unsigned short* __restrict__ hbuf,
    const int* __restrict__ cnt, const int* __restrict__ offs,
    const int* __restrict__ etok) {
    __shared__ alignas(16) unsigned short sA[2][BM * BK];   // 2 x 24 KB
    __shared__ alignas(16) unsigned short sBg[64 * BK];     // 4 KB
    __shared__ alignas(16) unsigned short sBu[64 * BK];     // 4 KB

    const int bx = blockIdx.x, t = threadIdx.x;
    const int lane = t & 63, w = t >> 6;
    const int wm = w >> 1, wn = w & 1;
    const int fr = lane & 15, fo = lane >> 4;

    const bool routed = bx >= GLU_SH;
    int n0, m_start, m_stop, obase, Ntot;
    const float *Bg, *Bu;
    unsigned short* outp;
    const int* etk = nullptr;
    if (routed) {
        int rx = bx - GLU_SH;
        int e = rx / 22; n0 = (rx % 22) * 64;
        int M = cnt[e];
        if (M <= 0) return;
        m_start = 0; m_stop = M; obase = offs[e]; Ntot = INTER;
        Bg = wg + ((size_t)e * INTER + n0) * HID;
        Bu = wu + ((size_t)e * INTER + n0) * HID;
        outp = abuf; etk = etok + e * TTOK;
    } else {
        n0 = (bx / 3) * 64;
        m_start = (bx % 3) * 768; m_stop = min(TTOK, m_start + 768);
        obase = 0; Ntot = SINTER;
        Bg = sg + (size_t)n0 * HID;
        Bu = su + (size_t)n0 * HID;
        outp = hbuf;
    }

    // B staging roles: waves 0-7 stage G rows 0..63, waves 8-15 stage U
    const int brow = (t & 511) >> 3;
    const float* srcB = (t < 512 ? Bg : Bu) + (size_t)brow * HID + (t & 7) * 4;
    char* sBrole = (t < 512 ? (char*)sBg : (char*)sBu);
    const unsigned wBo = (unsigned)(brow * 64 + (((t & 7) * 8) ^ ((brow & 3) << 4)));

    // fragment offsets (64B rows, slot-XOR swizzle)
    unsigned aoff[3], boff[2];
#pragma unroll
    for (int mi = 0; mi < 3; mi++) {
        int r = wm * 48 + mi * 16 + fr;
        aoff[mi] = (unsigned)(r * 64 + ((fo ^ (r & 3)) << 4));
    }
#pragma unroll
    for (int nj = 0; nj < 2; nj++) {
        int r = wn * 32 + nj * 16 + fr;
        boff[nj] = (unsigned)(r * 64 + ((fo ^ (r & 3)) << 4));
    }

    // A-stage lane geometry (pre-swizzled source chunk)
    const int arowin = lane >> 2;                       // 0..15
    const int achunk = (lane & 3) ^ (arowin & 3);

    for (int m0 = m_start; m0 < m_stop; m0 += BM) {
        const int rv = min(m_stop - m0, BM);
        const unsigned short* pA0 = nullptr; const unsigned short* pA1 = nullptr;
        if (w < 12) {
            int r0 = (w * 2) * 16 + arowin;
            int r1 = (w * 2 + 1) * 16 + arowin;
            int rr0 = r0 < rv ? r0 : rv - 1;
            int rr1 = r1 < rv ? r1 : rv - 1;
            int tok0 = routed ? (etk[m0 + rr0] >> 1) : (m0 + rr0);
            int tok1 = routed ? (etk[m0 + rr1] >> 1) : (m0 + rr1);
            pA0 = xb + (size_t)tok0 * HID + achunk * 8;
            pA1 = xb + (size_t)tok1 * HID + achunk * 8;
        }

        f32x4 ag[3][2], au[3][2];
#pragma unroll
        for (int mi = 0; mi < 3; mi++)
#pragma unroll
            for (int nj = 0; nj < 2; nj++) { ag[mi][nj] = {0.f,0.f,0.f,0.f}; au[mi][nj] = {0.f,0.f,0.f,0.f}; }

        // prologue: A(0) -> buf0, B(0) -> regs
        if (w < 12) {
            gload16(pA0, (char*)sA + (w * 2) * 1024);
            gload16(pA1, (char*)sA + (w * 2 + 1) * 1024);
        }
        float4 bC = *(const float4*)(srcB);
        float4 bN;

        for (int kk = 0; kk < HID / BK; ++kk) {
            const int cur = kk & 1;
            bsync();                                   // prev-iter reads complete
            if (kk + 1 < HID / BK) {
                const int k0n = (kk + 1) * BK;
                if (w < 12) {
                    gload16(pA0 + k0n, (char*)sA + (cur ^ 1) * 24576 + (w * 2) * 1024);
                    gload16(pA1 + k0n, (char*)sA + (cur ^ 1) * 24576 + (w * 2 + 1) * 1024);
                }
                bN = *(const float4*)(srcB + k0n);
                if (w < 12) WAIT_VM3; else WAIT_VM1;   // drain A(kk)+B(kk), keep (kk+1) in flight
            } else {
                WAIT_VM0;
            }
            {   // ds_write B(kk)
                ushort4 v;
                v.x = f2bf(bC.x); v.y = f2bf(bC.y); v.z = f2bf(bC.z); v.w = f2bf(bC.w);
                *(ushort4*)(sBrole + wBo) = v;
            }
            WAIT_LGKM0;
            bsync();                                   // A(kk) + B(kk) visible to all
            const char* sAc = (const char*)sA + cur * 24576;
            bf16x8 af[3], gf[2], uf[2];
#pragma unroll
            for (int mi = 0; mi < 3; mi++) af[mi] = *(const bf16x8*)(sAc + aoff[mi]);
#pragma unroll
            for (int nj = 0; nj < 2; nj++) {
                gf[nj] = *(const bf16x8*)((const char*)sBg + boff[nj]);
                uf[nj] = *(const bf16x8*)((const char*)sBu + boff[nj]);
            }
#pragma unroll
            for (int mi = 0; mi < 3; mi++)
#pragma unroll
                for (int nj = 0; nj < 2; nj++) {
                    ag[mi][nj] = __builtin_amdgcn_mfma_f32_16x16x32_bf16(af[mi], gf[nj], ag[mi][nj], 0, 0, 0);
                    au[mi][nj] = __builtin_amdgcn_mfma_f32_16x16x32_bf16(af[mi], uf[nj], au[mi][nj], 0, 0, 0);
                }
            bC = bN;
        }

        // epilogue: h = silu(g)*u -> stage bf16 [384][64] over the A buffers -> sweep
        bsync();
        char* sH = (char*)sA;
#pragma unroll
        for (int mi = 0; mi < 3; mi++)
#pragma unroll
            for (int jj = 0; jj < 4; jj++) {
                int r = wm * 48 + mi * 16 + fo * 4 + jj;
#pragma unroll
                for (int nj = 0; nj < 2; nj++) {
                    int c = wn * 32 + nj * 16 + fr;
                    float g = ag[mi][nj][jj];
                    float u = au[mi][nj][jj];
                    float h = (g / (1.f + __expf(-g))) * u;
                    *(unsigned short*)(sH + swz((unsigned)(r * 128 + c * 2))) = f2bf(h);
                }
            }
        WAIT_LGKM0;
        bsync();
#pragma unroll
        for (int q = 0; q < 3; q++) {
            int idx = q * 1024 + t;
            int r = idx >> 3, c = idx & 7;
            if (r < rv) {
                uint4 v = *(const uint4*)(sH + swz((unsigned)(r * 128 + c * 16)));
                *(uint4*)(outp + (size_t)(obase + m0 + r) * Ntot + n0 + c * 8) = v;
            }
        }
        WAIT_VM0;
        bsync();
    }
}

// Down GEMM. BM=384, BN=128, BK=32, 1024 thr. Same pipeline.
__global__ __launch_bounds__(1024) void k_down5(
    const unsigned short* __restrict__ abuf, const unsigned short* __restrict__ hbuf,
    const float* __restrict__ wd, const float* __restrict__ sd,
    unsigned short* __restrict__ slots,
    const int* __restrict__ cnt, const int* __restrict__ offs,
    const int* __restrict__ etok, const float* __restrict__ ew) {
    __shared__ alignas(16) unsigned short sA[2][BM * BK];   // 2 x 24 KB
    __shared__ alignas(16) unsigned short sB[128 * BK];     // 8 KB

    const int bx = blockIdx.x, t = threadIdx.x;
    const int lane = t & 63, w = t >> 6;
    const int wm = w >> 1, wn = w & 1;
    const int fr = lane & 15, fo = lane >> 4;

    const bool routed = bx >= DWN_SH;
    int n0, m_start, m_stop, K, KT;
    const float* W;
    const unsigned short* Abuf;
    size_t arow0 = 0;
    const int* etk = nullptr; const float* ewe = nullptr;
    if (routed) {
        int rx = bx - DWN_SH;
        int e = rx / 16; n0 = (rx % 16) * 128;
        int M = cnt[e];
        if (M <= 0) return;
        m_start = 0; m_stop = M;
        K = INTER; KT = INTER / BK;
        W = wd + (size_t)e * HID * INTER + (size_t)n0 * INTER;
        Abuf = abuf; arow0 = offs[e];
        etk = etok + e * TTOK; ewe = ew + e * TTOK;
    } else {
        n0 = (bx / 6) * 128;
        m_start = (bx % 6) * BM; m_stop = min(TTOK, m_start + BM);
        K = SINTER; KT = SINTER / BK;
        W = sd + (size_t)n0 * SINTER;
        Abuf = hbuf;
    }

    const int brow = t >> 3;                            // 0..127
    const float* srcB = W + (size_t)brow * K + (t & 7) * 4;
    const unsigned wBo = (unsigned)(brow * 64 + (((t & 7) * 8) ^ ((brow & 3) << 4)));

    unsigned aoff[3], boff[4];
#pragma unroll
    for (int mi = 0; mi < 3; mi++) {
        int r = wm * 48 + mi * 16 + fr;
        aoff[mi] = (unsigned)(r * 64 + ((fo ^ (r & 3)) << 4));
    }
#pragma unroll
    for (int nj = 0; nj < 4; nj++) {
        int r = wn * 64 + nj * 16 + fr;
        boff[nj] = (unsigned)(r * 64 + ((fo ^ (r & 3)) << 4));
    }

    const int arowin = lane >> 2;
    const int achunk = (lane & 3) ^ (arowin & 3);

    for (int m0 = m_start; m0 < m_stop; m0 += BM) {
        const int rv = min(m_stop - m0, BM);
        const unsigned short* pA0 = nullptr; const unsigned short* pA1 = nullptr;
        if (w < 12) {
            int r0 = (w * 2) * 16 + arowin;
            int r1 = (w * 2 + 1) * 16 + arowin;
            int rr0 = r0 < rv ? r0 : rv - 1;
            int rr1 = r1 < rv ? r1 : rv - 1;
            pA0 = Abuf + (arow0 + m0 + rr0) * (size_t)K + achunk * 8;
            pA1 = Abuf + (arow0 + m0 + rr1) * (size_t)K + achunk * 8;
        }

        f32x4 ac[3][4];
#pragma unroll
        for (int mi = 0; mi < 3; mi++)
#pragma unroll
            for (int nj = 0; nj < 4; nj++) ac[mi][nj] = {0.f, 0.f, 0.f, 0.f};

        if (w < 12) {
            gload16(pA0, (char*)sA + (w * 2) * 1024);
            gload16(pA1, (char*)sA + (w * 2 + 1) * 1024);
        }
        float4 bC = *(const float4*)(srcB);
        float4 bN;

        for (int kk = 0; kk < KT; ++kk) {
            const int cur = kk & 1;
            bsync();
            if (kk + 1 < KT) {
                const int k0n = (kk + 1) * BK;
                if (w < 12) {
                    gload16(pA0 + k0n, (char*)sA + (cur ^ 1) * 24576 + (w * 2) * 1024);
                    gload16(pA1 + k0n, (char*)sA + (cur ^ 1) * 24576 + (w * 2 + 1) * 1024);
                }
                bN = *(const float4*)(srcB + k0n);
                if (w < 12) WAIT_VM3; else WAIT_VM1;
            } else {
                WAIT_VM0;
            }
            {
                ushort4 v;
                v.x = f2bf(bC.x); v.y = f2bf(bC.y); v.z = f2bf(bC.z); v.w = f2bf(bC.w);
                *(ushort4*)((char*)sB + wBo) = v;
            }
            WAIT_LGKM0;
            bsync();
            const char* sAc = (const char*)sA + cur * 24576;
            bf16x8 af[3], bf[4];
#pragma unroll
            for (int mi = 0; mi < 3; mi++) af[mi] = *(const bf16x8*)(sAc + aoff[mi]);
#pragma unroll
            for (int nj = 0; nj < 4; nj++) bf[nj] = *(const bf16x8*)((const char*)sB + boff[nj]);
#pragma unroll
            for (int mi = 0; mi < 3; mi++)
#pragma unroll
                for (int nj = 0; nj < 4; nj++)
                    ac[mi][nj] = __builtin_amdgcn_mfma_f32_16x16x32_bf16(af[mi], bf[nj], ac[mi][nj], 0, 0, 0);
            bC = bN;
        }

        // epilogue: two 64-col passes staged over the A buffers
        bsync();
        char* sH = (char*)sA;
#pragma unroll
        for (int p = 0; p < 2; p++) {
            if (wn == p) {
#pragma unroll
                for (int mi = 0; mi < 3; mi++)
#pragma unroll
                    for (int jj = 0; jj < 4; jj++) {
                        int r = wm * 48 + mi * 16 + fo * 4 + jj;
                        float wt = 1.f;
                        if (routed) wt = (r < rv) ? ewe[m0 + r] : 0.f;
#pragma unroll
                        for (int nj = 0; nj < 4; nj++) {
                            int c = nj * 16 + fr;
                            *(unsigned short*)(sH + swz((unsigned)(r * 128 + c * 2))) =
                                f2bf(ac[mi][nj][jj] * wt);
                        }
                    }
            }
            WAIT_LGKM0;
            bsync();
#pragma unroll
            for (int q = 0; q < 3; q++) {
                int idx = q * 1024 + t;
                int r = idx >> 3, c = idx & 7;
                if (r < rv) {
                    uint4 v = *(const uint4*)(sH + swz((unsigned)(r * 128 + c * 16)));
                    int tok, slice;
                    if (routed) { int entry = etk[m0 + r]; tok = entry >> 1; slice = entry & 1; }
                    else        { tok = m0 + r; slice = 2; }
                    *(uint4*)(slots + ((size_t)slice * TTOK + tok) * HID + n0 + p * 64 + c * 8) = v;
                }
            }
            bsync();
        }
        WAIT_VM0;
        bsync();
    }
}

__global__ __launch_bounds__(256) void k_final(float* __restrict__ out,
                                               const unsigned short* __restrict__ slots) {
    size_t i = ((size_t)blockIdx.x * 256 + threadIdx.x) * 8;
    u16x8 s0 = *(const u16x8*)(slots + i);
    u16x8 s1 = *(const u16x8*)(slots + (size_t)TTOK * HID + i);
    u16x8 s2 = *(const u16x8*)(slots + (size_t)2 * TTOK * HID + i);
    float4 o0, o1;
    o0.x = bf2f(s0[0]) + bf2f(s1[0]) + bf2f(s2[0]);
    o0.y = bf2f(s0[1]) + bf2f(s1[1]) + bf2f(s2[1]);
    o0.z = bf2f(s0[2]) + bf2f(s1[2]) + bf2f(s2[2]);
    o0.w = bf2f(s0[3]) + bf2f(s1[3]) + bf2f(s2[3]);
    o1.x = bf2f(s0[4]) + bf2f(s1[4]) + bf2f(s2[4]);
    o1.y = bf2f(s0[5]) + bf2f(s1[5]) + bf2f(s2[5]);
    o1.z = bf2f(s0[6]) + bf2f(s1[6]) + bf2f(s2[6]);
    o1.w = bf2f(s0[7]) + bf2f(s1[7]) + bf2f(s2[7]);
    *(float4*)(out + i) = o0;
    *(float4*)(out + i + 4) = o1;
}

extern "C" void kernel_launch(void* const* d_in, const int* in_sizes, int n_in,
                              void* d_out, int out_size, void* d_ws, size_t ws_size,
                              hipStream_t stream) {
    const float* x = (const float*)d_in[0];
    const float* gate_w = (const float*)d_in[1];
    const float* cls_w = (const float*)d_in[2];
    const float* escale = (const float*)d_in[3];
    const float* ebias = (const float*)d_in[4];
    const float* wg = (const float*)d_in[5];
    const float* wu = (const float*)d_in[6];
    const float* wd = (const float*)d_in[7];
    const float* sg = (const float*)d_in[8];
    const float* su = (const float*)d_in[9];
    const float* sd = (const float*)d_in[10];
    float* out = (float*)d_out;

    char* ws = (char*)d_ws;
    size_t o = 0;
    auto alloc = [&](size_t bytes) {
        char* p = ws + o;
        o += (bytes + 255) & ~(size_t)255;
        return p;
    };
    unsigned short* xb    = (unsigned short*)alloc((size_t)TTOK * HID * 2);        // 8 MB
    unsigned short* hbuf  = (unsigned short*)alloc((size_t)TTOK * SINTER * 2);     // 11.5 MB
    unsigned short* abuf  = (unsigned short*)alloc((size_t)2 * TTOK * INTER * 2);  // 11.5 MB
    unsigned short* slots = (unsigned short*)alloc((size_t)3 * TTOK * HID * 2);    // 24 MB
    int* cnt              = (int*)alloc(256);
    int* offs             = (int*)alloc(256);
    int* etok             = (int*)alloc((size_t)NEXP * TTOK * 4);
    float* ew             = (float*)alloc((size_t)NEXP * TTOK * 4);

    k_zero<<<1, 64, 0, stream>>>(cnt);
    k_xcvt<<<2048, 256, 0, stream>>>(x, xb);
    k_router<<<512, 256, 0, stream>>>(x, gate_w, cls_w, escale, ebias, cnt, etok, ew);
    k_offsets<<<1, 64, 0, stream>>>(cnt, offs);
    k_glu5<<<GLU_SH + GLU_RT, 1024, 0, stream>>>(
        xb, wg, wu, sg, su, abuf, hbuf, cnt, offs, etok);
    k_down5<<<DWN_SH + DWN_RT, 1024, 0, stream>>>(
        abuf, hbuf, wd, sd, slots, cnt, offs, etok, ew);
    k_final<<<2048, 256, 0, stream>>>(out, slots);
}

// Round 6
// 650.106 us; speedup vs baseline: 1.2649x; 1.2649x over previous
//
#include <hip/hip_runtime.h>

#define HID 2048
#define INTER 1408
#define NEXP 14
#define SINTER 2816
#define TTOK 2048
#define BM 384
#define BK 64

#define GLU_SH 264   // 44 n-tiles x 6 m-slices (shared, scheduled first)
#define GLU_RT 308   // 22 n-tiles x 14 experts
#define DWN_SH 192   // 32 n-tiles x 6 m-slices
#define DWN_RT 448   // 32 n-tiles x 14 experts

typedef short bf16x8 __attribute__((ext_vector_type(8)));
typedef float f32x4 __attribute__((ext_vector_type(4)));
typedef unsigned short u16x8 __attribute__((ext_vector_type(8)));

__device__ __forceinline__ unsigned short f2bf(float f) {
    __bf16 b = (__bf16)f;
    return __builtin_bit_cast(unsigned short, b);
}
__device__ __forceinline__ float bf2f(unsigned short u) {
    unsigned v = (unsigned)u << 16;
    return __builtin_bit_cast(float, v);
}
// XOR swizzle for 128B-stride rows (proven conflict-free in R4)
__device__ __forceinline__ unsigned swz(unsigned b) { return b ^ (((b >> 7) & 7u) << 4); }

__device__ __forceinline__ void gload16(const void* g, void* l) {
    __builtin_amdgcn_global_load_lds((__attribute__((address_space(1))) void*)g,
                                     (__attribute__((address_space(3))) void*)l, 16, 0, 0);
}
// raw barrier, fenced against compiler motion; does NOT drain vmcnt
__device__ __forceinline__ void bsync() {
    __builtin_amdgcn_sched_barrier(0);
    __builtin_amdgcn_s_barrier();
    __builtin_amdgcn_sched_barrier(0);
}
#define WAIT_LGKM0 asm volatile("s_waitcnt lgkmcnt(0)" ::: "memory")

__global__ void k_zero(int* cnt) {
    if ((int)threadIdx.x < NEXP) cnt[threadIdx.x] = 0;
}

__global__ __launch_bounds__(256) void k_xcvt(const float* __restrict__ x,
                                              unsigned short* __restrict__ xb) {
    size_t i = ((size_t)blockIdx.x * 256 + threadIdx.x) * 8;
    float4 a = *(const float4*)(x + i);
    float4 b = *(const float4*)(x + i + 4);
    u16x8 v;
    v[0] = f2bf(a.x); v[1] = f2bf(a.y); v[2] = f2bf(a.z); v[3] = f2bf(a.w);
    v[4] = f2bf(b.x); v[5] = f2bf(b.y); v[6] = f2bf(b.z); v[7] = f2bf(b.w);
    *(u16x8*)(xb + i) = v;
}

__global__ __launch_bounds__(256) void k_router(
    const float* __restrict__ x,
    const float* __restrict__ gate_w, const float* __restrict__ cls_w,
    const float* __restrict__ escale, const float* __restrict__ ebias,
    int* __restrict__ cnt, int* __restrict__ etok, float* __restrict__ ew) {
    const int lane = threadIdx.x & 63;
    const int tok = blockIdx.x * 4 + (threadIdx.x >> 6);
    const float* xr = x + (size_t)tok * HID;
    float xv[32];
#pragma unroll
    for (int i = 0; i < 32; i++) xv[i] = xr[lane + 64 * i];

    float sc[NEXP];
    float mx = 0.f;
#pragma unroll
    for (int e = 0; e < NEXP; e++) {
        const float* cw = cls_w + (size_t)e * HID;
        const float* gw = gate_w + (size_t)e * HID;
        float pc = 0.f, pg = 0.f;
#pragma unroll
        for (int i = 0; i < 32; i++) {
            float v = xv[i];
            pc = fmaf(v, cw[lane + 64 * i], pc);
            pg = fmaf(v, gw[lane + 64 * i], pg);
        }
#pragma unroll
        for (int o = 32; o >= 1; o >>= 1) {
            pc += __shfl_xor(pc, o);
            pg += __shfl_xor(pg, o);
        }
        float lg = pc * (pg / (1.f + __expf(-pg)));
        sc[e] = fabsf(lg);
        mx = fmaxf(mx, sc[e]);
    }
    float s = 0.f;
#pragma unroll
    for (int e = 0; e < NEXP; e++) { sc[e] = __expf(sc[e] - mx); s += sc[e]; }
    float inv = 1.f / s;
    int i1 = -1, i2 = -1;
    float b1 = -1e30f, b2 = -1e30f, v1 = 0.f, v2 = 0.f;
#pragma unroll
    for (int e = 0; e < NEXP; e++) {
        float sv = sc[e] * inv;
        float b = sv + ebias[e];
        if (b > b1) { b2 = b1; i2 = i1; v2 = v1; b1 = b; i1 = e; v1 = sv; }
        else if (b > b2) { b2 = b; i2 = e; v2 = sv; }
    }
    if (lane == 0) {
        float w1 = 1.f + v1 * escale[i1];
        float w2 = 1.f + v2 * escale[i2];
        int p1 = atomicAdd(&cnt[i1], 1);
        etok[i1 * TTOK + p1] = tok * 2;     ew[i1 * TTOK + p1] = w1;
        int p2 = atomicAdd(&cnt[i2], 1);
        etok[i2 * TTOK + p2] = tok * 2 + 1; ew[i2 * TTOK + p2] = w2;
    }
}

__global__ void k_offsets(const int* __restrict__ cnt, int* __restrict__ offs) {
    if (threadIdx.x == 0) {
        int a = 0;
        for (int e = 0; e < NEXP; e++) { offs[e] = a; a += cnt[e]; }
    }
}

// Gate+up GEMM. BM=384, BN=64 (per matrix), BK=64, 1024 thr / 16 waves (8m x 2n).
// A: dbuf via global_load_lds, one-iter prefetch. B: fp32->bf16 reg-carried one iter.
__global__ __launch_bounds__(1024) void k_glu6(
    const unsigned short* __restrict__ xb,
    const float* __restrict__ wg, const float* __restrict__ wu,
    const float* __restrict__ sg, const float* __restrict__ su,
    unsigned short* __restrict__ abuf, unsigned short* __restrict__ hbuf,
    const int* __restrict__ cnt, const int* __restrict__ offs,
    const int* __restrict__ etok) {
    __shared__ alignas(16) unsigned short sA[2][BM * BK];   // 2 x 48 KB
    __shared__ alignas(16) unsigned short sBg[64 * BK];     // 8 KB
    __shared__ alignas(16) unsigned short sBu[64 * BK];     // 8 KB

    const int bx = blockIdx.x, t = threadIdx.x;
    const int lane = t & 63, w = t >> 6;
    const int wm = w >> 1, wn = w & 1;
    const int fr = lane & 15, fo = lane >> 4;

    const bool routed = bx >= GLU_SH;
    int n0, m_start, m_stop, obase, Ntot;
    const float *Bg, *Bu;
    unsigned short* outp;
    const int* etk = nullptr;
    if (routed) {
        int rx = bx - GLU_SH;
        int e = rx / 22; n0 = (rx % 22) * 64;
        int M = cnt[e];
        if (M <= 0) return;
        m_start = 0; m_stop = M; obase = offs[e]; Ntot = INTER;
        Bg = wg + ((size_t)e * INTER + n0) * HID;
        Bu = wu + ((size_t)e * INTER + n0) * HID;
        outp = abuf; etk = etok + e * TTOK;
    } else {
        n0 = (bx / 6) * 64;
        m_start = (bx % 6) * BM; m_stop = min(TTOK, m_start + BM);
        obase = 0; Ntot = SINTER;
        Bg = sg + (size_t)n0 * HID;
        Bu = su + (size_t)n0 * HID;
        outp = hbuf;
    }

    // B staging: thread -> row t>>4 (0..63), 4 floats of G and of U
    const int brow = t >> 4, bc4 = (t & 15) * 4;
    const float* srcG = Bg + (size_t)brow * HID + bc4;
    const float* srcU = Bu + (size_t)brow * HID + bc4;
    const unsigned wBo = swz((unsigned)(brow * 128 + bc4 * 2));

    unsigned aoff[3][2], boff[2][2];
#pragma unroll
    for (int mi = 0; mi < 3; mi++)
#pragma unroll
        for (int ks = 0; ks < 2; ks++)
            aoff[mi][ks] = swz((unsigned)((wm * 48 + mi * 16 + fr) * 128 + ks * 64 + fo * 16));
#pragma unroll
    for (int nj = 0; nj < 2; nj++)
#pragma unroll
        for (int ks = 0; ks < 2; ks++)
            boff[nj][ks] = swz((unsigned)((wn * 32 + nj * 16 + fr) * 128 + ks * 64 + fo * 16));

    // A gload geometry: wave w issue j covers LDS rows (w*3+j)*8..+7; pre-swizzled chunk
    const int arow_off = lane >> 3;
    const int achunk = (lane & 7) ^ arow_off;

    for (int m0 = m_start; m0 < m_stop; m0 += BM) {
        const int rv = min(m_stop - m0, BM);
        const unsigned short* srcA[3];
#pragma unroll
        for (int j = 0; j < 3; j++) {
            int r = (w * 3 + j) * 8 + arow_off;
            int rr = r < rv ? r : rv - 1;
            int tok = routed ? (etk[m0 + rr] >> 1) : (m0 + rr);
            srcA[j] = xb + (size_t)tok * HID + achunk * 8;
        }

        f32x4 ag[3][2], au[3][2];
#pragma unroll
        for (int mi = 0; mi < 3; mi++)
#pragma unroll
            for (int nj = 0; nj < 2; nj++) { ag[mi][nj] = {0.f,0.f,0.f,0.f}; au[mi][nj] = {0.f,0.f,0.f,0.f}; }

        // prologue: A(0) -> buf0, B(0) -> regs
#pragma unroll
        for (int j = 0; j < 3; j++)
            gload16(srcA[j], (char*)sA + (w * 3 + j) * 1024);
        float4 gC = *(const float4*)(srcG);
        float4 uC = *(const float4*)(srcU);
        float4 gN, uN;

        for (int kk = 0; kk < HID / BK; ++kk) {
            const int cur = kk & 1;
            bsync();                       // all waves done reading LDS of iter kk-1
            if (kk + 1 < HID / BK) {       // issue prefetch of (kk+1)
                const int k0n = (kk + 1) * BK;
#pragma unroll
                for (int j = 0; j < 3; j++)
                    gload16(srcA[j] + k0n, (char*)sA + (cur ^ 1) * (BM * BK * 2) + (w * 3 + j) * 1024);
                gN = *(const float4*)(srcG + k0n);
                uN = *(const float4*)(srcU + k0n);
            }
            __builtin_amdgcn_sched_barrier(0);   // keep prefetch issue above the B(k) use
            {   // ds_write B(kk) from carried regs (auto-wait is counted: 5 newer loads)
                ushort4 vg, vu;
                vg.x = f2bf(gC.x); vg.y = f2bf(gC.y); vg.z = f2bf(gC.z); vg.w = f2bf(gC.w);
                vu.x = f2bf(uC.x); vu.y = f2bf(uC.y); vu.z = f2bf(uC.z); vu.w = f2bf(uC.w);
                *(ushort4*)((char*)sBg + wBo) = vg;
                *(ushort4*)((char*)sBu + wBo) = vu;
            }
            WAIT_LGKM0;
            bsync();                       // A(kk) + B(kk) visible to all waves
            const char* sAc = (const char*)sA + cur * (BM * BK * 2);
#pragma unroll
            for (int ks = 0; ks < 2; ++ks) {
                bf16x8 af[3], gf[2], uf[2];
#pragma unroll
                for (int mi = 0; mi < 3; mi++) af[mi] = *(const bf16x8*)(sAc + aoff[mi][ks]);
#pragma unroll
                for (int nj = 0; nj < 2; nj++) {
                    gf[nj] = *(const bf16x8*)((const char*)sBg + boff[nj][ks]);
                    uf[nj] = *(const bf16x8*)((const char*)sBu + boff[nj][ks]);
                }
#pragma unroll
                for (int mi = 0; mi < 3; mi++)
#pragma unroll
                    for (int nj = 0; nj < 2; nj++) {
                        ag[mi][nj] = __builtin_amdgcn_mfma_f32_16x16x32_bf16(af[mi], gf[nj], ag[mi][nj], 0, 0, 0);
                        au[mi][nj] = __builtin_amdgcn_mfma_f32_16x16x32_bf16(af[mi], uf[nj], au[mi][nj], 0, 0, 0);
                    }
            }
            gC = gN; uC = uN;
        }

        // epilogue: h = silu(g)*u -> stage bf16 [384][64] in buf0 -> coalesced sweep
        char* sH = (char*)sA;              // disjoint from buf1 (last MFMA reads buf1)
#pragma unroll
        for (int mi = 0; mi < 3; mi++)
#pragma unroll
            for (int jj = 0; jj < 4; jj++) {
                int r = wm * 48 + mi * 16 + fo * 4 + jj;
#pragma unroll
                for (int nj = 0; nj < 2; nj++) {
                    int c = wn * 32 + nj * 16 + fr;
                    float g = ag[mi][nj][jj];
                    float u = au[mi][nj][jj];
                    float h = (g / (1.f + __expf(-g))) * u;
                    *(unsigned short*)(sH + swz((unsigned)(r * 128 + c * 2))) = f2bf(h);
                }
            }
        WAIT_LGKM0;
        bsync();
#pragma unroll
        for (int q = 0; q < 3; q++) {
            int idx = q * 1024 + t;
            int r = idx >> 3, c = idx & 7;
            if (r < rv) {
                uint4 v = *(const uint4*)(sH + swz((unsigned)(r * 128 + c * 16)));
                *(uint4*)(outp + (size_t)(obase + m0 + r) * Ntot + n0 + c * 8) = v;
            }
        }
        bsync();                           // sweep reads done before next slice's gloads land
    }
}

// Down GEMM. BM=384, BN=64, BK=64, 1024 thr / 16 waves. Same pipeline.
__global__ __launch_bounds__(1024) void k_down6(
    const unsigned short* __restrict__ abuf, const unsigned short* __restrict__ hbuf,
    const float* __restrict__ wd, const float* __restrict__ sd,
    unsigned short* __restrict__ slots,
    const int* __restrict__ cnt, const int* __restrict__ offs,
    const int* __restrict__ etok, const float* __restrict__ ew) {
    __shared__ alignas(16) unsigned short sA[2][BM * BK];   // 2 x 48 KB
    __shared__ alignas(16) unsigned short sB[64 * BK];      // 8 KB

    const int bx = blockIdx.x, t = threadIdx.x;
    const int lane = t & 63, w = t >> 6;
    const int wm = w >> 1, wn = w & 1;
    const int fr = lane & 15, fo = lane >> 4;

    const bool routed = bx >= DWN_SH;
    int n0, m_start, m_stop, K, KT;
    const float* W;
    const unsigned short* Abuf;
    size_t arow0 = 0;
    const int* etk = nullptr; const float* ewe = nullptr;
    if (routed) {
        int rx = bx - DWN_SH;
        int e = rx / 32; n0 = (rx % 32) * 64;
        int M = cnt[e];
        if (M <= 0) return;
        m_start = 0; m_stop = M;
        K = INTER; KT = INTER / BK;
        W = wd + (size_t)e * HID * INTER + (size_t)n0 * INTER;
        Abuf = abuf; arow0 = offs[e];
        etk = etok + e * TTOK; ewe = ew + e * TTOK;
    } else {
        n0 = (bx / 6) * 64;
        m_start = (bx % 6) * BM; m_stop = min(TTOK, m_start + BM);
        K = SINTER; KT = SINTER / BK;
        W = sd + (size_t)n0 * SINTER;
        Abuf = hbuf;
    }

    const int brow = t >> 4, bc4 = (t & 15) * 4;
    const float* srcB = W + (size_t)brow * K + bc4;
    const unsigned wBo = swz((unsigned)(brow * 128 + bc4 * 2));

    unsigned aoff[3][2], boff[2][2];
#pragma unroll
    for (int mi = 0; mi < 3; mi++)
#pragma unroll
        for (int ks = 0; ks < 2; ks++)
            aoff[mi][ks] = swz((unsigned)((wm * 48 + mi * 16 + fr) * 128 + ks * 64 + fo * 16));
#pragma unroll
    for (int nj = 0; nj < 2; nj++)
#pragma unroll
        for (int ks = 0; ks < 2; ks++)
            boff[nj][ks] = swz((unsigned)((wn * 32 + nj * 16 + fr) * 128 + ks * 64 + fo * 16));

    const int arow_off = lane >> 3;
    const int achunk = (lane & 7) ^ arow_off;

    for (int m0 = m_start; m0 < m_stop; m0 += BM) {
        const int rv = min(m_stop - m0, BM);
        const unsigned short* srcA[3];
#pragma unroll
        for (int j = 0; j < 3; j++) {
            int r = (w * 3 + j) * 8 + arow_off;
            int rr = r < rv ? r : rv - 1;
            srcA[j] = Abuf + (arow0 + m0 + rr) * (size_t)K + achunk * 8;
        }

        f32x4 ac[3][2];
#pragma unroll
        for (int mi = 0; mi < 3; mi++)
#pragma unroll
            for (int nj = 0; nj < 2; nj++) ac[mi][nj] = {0.f, 0.f, 0.f, 0.f};

#pragma unroll
        for (int j = 0; j < 3; j++)
            gload16(srcA[j], (char*)sA + (w * 3 + j) * 1024);
        float4 bC = *(const float4*)(srcB);
        float4 bN;

        for (int kk = 0; kk < KT; ++kk) {
            const int cur = kk & 1;
            bsync();
            if (kk + 1 < KT) {
                const int k0n = (kk + 1) * BK;
#pragma unroll
                for (int j = 0; j < 3; j++)
                    gload16(srcA[j] + k0n, (char*)sA + (cur ^ 1) * (BM * BK * 2) + (w * 3 + j) * 1024);
                bN = *(const float4*)(srcB + k0n);
            }
            __builtin_amdgcn_sched_barrier(0);
            {
                ushort4 v;
                v.x = f2bf(bC.x); v.y = f2bf(bC.y); v.z = f2bf(bC.z); v.w = f2bf(bC.w);
                *(ushort4*)((char*)sB + wBo) = v;
            }
            WAIT_LGKM0;
            bsync();
            const char* sAc = (const char*)sA + cur * (BM * BK * 2);
#pragma unroll
            for (int ks = 0; ks < 2; ++ks) {
                bf16x8 af[3], bf[2];
#pragma unroll
                for (int mi = 0; mi < 3; mi++) af[mi] = *(const bf16x8*)(sAc + aoff[mi][ks]);
#pragma unroll
                for (int nj = 0; nj < 2; nj++) bf[nj] = *(const bf16x8*)((const char*)sB + boff[nj][ks]);
#pragma unroll
                for (int mi = 0; mi < 3; mi++)
#pragma unroll
                    for (int nj = 0; nj < 2; nj++)
                        ac[mi][nj] = __builtin_amdgcn_mfma_f32_16x16x32_bf16(af[mi], bf[nj], ac[mi][nj], 0, 0, 0);
            }
            bC = bN;
        }

        // epilogue: scale, stage bf16 [384][64] in buf0, sweep to slot slices
        char* sH = (char*)sA;
#pragma unroll
        for (int mi = 0; mi < 3; mi++)
#pragma unroll
            for (int jj = 0; jj < 4; jj++) {
                int r = wm * 48 + mi * 16 + fo * 4 + jj;
                float wt = 1.f;
                if (routed) wt = (r < rv) ? ewe[m0 + r] : 0.f;
#pragma unroll
                for (int nj = 0; nj < 2; nj++) {
                    int c = wn * 32 + nj * 16 + fr;
                    *(unsigned short*)(sH + swz((unsigned)(r * 128 + c * 2))) =
                        f2bf(ac[mi][nj][jj] * wt);
                }
            }
        WAIT_LGKM0;
        bsync();
#pragma unroll
        for (int q = 0; q < 3; q++) {
            int idx = q * 1024 + t;
            int r = idx >> 3, c = idx & 7;
            if (r < rv) {
                uint4 v = *(const uint4*)(sH + swz((unsigned)(r * 128 + c * 16)));
                int tok, slice;
                if (routed) { int entry = etk[m0 + r]; tok = entry >> 1; slice = entry & 1; }
                else        { tok = m0 + r; slice = 2; }
                *(uint4*)(slots + ((size_t)slice * TTOK + tok) * HID + n0 + c * 8) = v;
            }
        }
        bsync();
    }
}

__global__ __launch_bounds__(256) void k_final(float* __restrict__ out,
                                               const unsigned short* __restrict__ slots) {
    size_t i = ((size_t)blockIdx.x * 256 + threadIdx.x) * 8;
    u16x8 s0 = *(const u16x8*)(slots + i);
    u16x8 s1 = *(const u16x8*)(slots + (size_t)TTOK * HID + i);
    u16x8 s2 = *(const u16x8*)(slots + (size_t)2 * TTOK * HID + i);
    float4 o0, o1;
    o0.x = bf2f(s0[0]) + bf2f(s1[0]) + bf2f(s2[0]);
    o0.y = bf2f(s0[1]) + bf2f(s1[1]) + bf2f(s2[1]);
    o0.z = bf2f(s0[2]) + bf2f(s1[2]) + bf2f(s2[2]);
    o0.w = bf2f(s0[3]) + bf2f(s1[3]) + bf2f(s2[3]);
    o1.x = bf2f(s0[4]) + bf2f(s1[4]) + bf2f(s2[4]);
    o1.y = bf2f(s0[5]) + bf2f(s1[5]) + bf2f(s2[5]);
    o1.z = bf2f(s0[6]) + bf2f(s1[6]) + bf2f(s2[6]);
    o1.w = bf2f(s0[7]) + bf2f(s1[7]) + bf2f(s2[7]);
    *(float4*)(out + i) = o0;
    *(float4*)(out + i + 4) = o1;
}

extern "C" void kernel_launch(void* const* d_in, const int* in_sizes, int n_in,
                              void* d_out, int out_size, void* d_ws, size_t ws_size,
                              hipStream_t stream) {
    const float* x = (const float*)d_in[0];
    const float* gate_w = (const float*)d_in[1];
    const float* cls_w = (const float*)d_in[2];
    const float* escale = (const float*)d_in[3];
    const float* ebias = (const float*)d_in[4];
    const float* wg = (const float*)d_in[5];
    const float* wu = (const float*)d_in[6];
    const float* wd = (const float*)d_in[7];
    const float* sg = (const float*)d_in[8];
    const float* su = (const float*)d_in[9];
    const float* sd = (const float*)d_in[10];
    float* out = (float*)d_out;

    char* ws = (char*)d_ws;
    size_t o = 0;
    auto alloc = [&](size_t bytes) {
        char* p = ws + o;
        o += (bytes + 255) & ~(size_t)255;
        return p;
    };
    unsigned short* xb    = (unsigned short*)alloc((size_t)TTOK * HID * 2);        // 8 MB
    unsigned short* hbuf  = (unsigned short*)alloc((size_t)TTOK * SINTER * 2);     // 11.5 MB
    unsigned short* abuf  = (unsigned short*)alloc((size_t)2 * TTOK * INTER * 2);  // 11.5 MB
    unsigned short* slots = (unsigned short*)alloc((size_t)3 * TTOK * HID * 2);    // 24 MB
    int* cnt              = (int*)alloc(256);
    int* offs             = (int*)alloc(256);
    int* etok             = (int*)alloc((size_t)NEXP * TTOK * 4);
    float* ew             = (float*)alloc((size_t)NEXP * TTOK * 4);

    k_zero<<<1, 64, 0, stream>>>(cnt);
    k_xcvt<<<2048, 256, 0, stream>>>(x, xb);
    k_router<<<512, 256, 0, stream>>>(x, gate_w, cls_w, escale, ebias, cnt, etok, ew);
    k_offsets<<<1, 64, 0, stream>>>(cnt, offs);
    k_glu6<<<GLU_SH + GLU_RT, 1024, 0, stream>>>(
        xb, wg, wu, sg, su, abuf, hbuf, cnt, offs, etok);
    k_down6<<<DWN_SH + DWN_RT, 1024, 0, stream>>>(
        abuf, hbuf, wd, sd, slots, cnt, offs, etok, ew);
    k_final<<<2048, 256, 0, stream>>>(out, slots);
}